// Round 2
// baseline (175.733 us; speedup 1.0000x reference)
//
#include <hip/hip_runtime.h>
#include <math.h>

#define NBINS 15

// accum layout in d_ws (48 floats): [0..14] counts, [16..30] sum_conf, [32..46] sum_acc
__global__ void ece_init(float* accum) {
    int t = threadIdx.x;
    if (t < 48) accum[t] = 0.0f;
}

__global__ __launch_bounds__(256) void ece_main(
    const float* __restrict__ logits,
    const int* __restrict__ labels,
    const float* __restrict__ temp,
    float* __restrict__ accum,
    int N)
{
    const float invT = 1.0f / temp[0];
    const int tid  = threadIdx.x;
    const int lane = tid & 63;
    const int c    = lane & 15;   // position within 16-lane group
    const int g    = lane >> 4;   // which of the wave's 4 rows
    const int wavesPerBlock = blockDim.x >> 6;
    const long long waveId     = (long long)blockIdx.x * wavesPerBlock + (tid >> 6);
    const long long totalWaves = (long long)gridDim.x * wavesPerBlock;

    float cnt = 0.f, sconf = 0.f, sacc = 0.f;
    const bool has2 = (c < 9);  // 100 floats = 16 float4 + 9 float4

    for (long long base = waveId * 4; base < (long long)N; base += totalWaves * 4) {
        long long row = base + g;
        const bool valid = (row < (long long)N);
        const long long r = valid ? row : (long long)(N - 1);
        const float* rowp = logits + (size_t)r * 100;

        float4 a = *reinterpret_cast<const float4*>(rowp + 4 * c);
        float4 b;
        if (has2) {
            b = *reinterpret_cast<const float4*>(rowp + 64 + 4 * c);
        } else {
            b = make_float4(-INFINITY, -INFINITY, -INFINITY, -INFINITY);
        }
        a.x *= invT; a.y *= invT; a.z *= invT; a.w *= invT;
        b.x *= invT; b.y *= invT; b.z *= invT; b.w *= invT;

        // local first-argmax (strict > keeps lowest index on ties)
        float lm = a.x; int lidx = 4 * c;
        if (a.y > lm) { lm = a.y; lidx = 4 * c + 1; }
        if (a.z > lm) { lm = a.z; lidx = 4 * c + 2; }
        if (a.w > lm) { lm = a.w; lidx = 4 * c + 3; }
        if (b.x > lm) { lm = b.x; lidx = 64 + 4 * c; }
        if (b.y > lm) { lm = b.y; lidx = 64 + 4 * c + 1; }
        if (b.z > lm) { lm = b.z; lidx = 64 + 4 * c + 2; }
        if (b.w > lm) { lm = b.w; lidx = 64 + 4 * c + 3; }

        // 16-lane all-reduce max
        float gm = lm;
        gm = fmaxf(gm, __shfl_xor(gm, 1));
        gm = fmaxf(gm, __shfl_xor(gm, 2));
        gm = fmaxf(gm, __shfl_xor(gm, 4));
        gm = fmaxf(gm, __shfl_xor(gm, 8));

        // first global index achieving gm
        int cand = (lm == gm) ? lidx : 0x7fffffff;
        cand = min(cand, __shfl_xor(cand, 1));
        cand = min(cand, __shfl_xor(cand, 2));
        cand = min(cand, __shfl_xor(cand, 4));
        cand = min(cand, __shfl_xor(cand, 8));

        // sum of exp(l - gm); confidence = 1/sum
        float s = __expf(a.x - gm) + __expf(a.y - gm)
                + __expf(a.z - gm) + __expf(a.w - gm);
        if (has2) {
            s += __expf(b.x - gm) + __expf(b.y - gm)
               + __expf(b.z - gm) + __expf(b.w - gm);
        }
        s += __shfl_xor(s, 1);
        s += __shfl_xor(s, 2);
        s += __shfl_xor(s, 4);
        s += __shfl_xor(s, 8);

        float conf = 1.0f / s;
        int  lbl  = labels[r];
        float acc = (cand == lbl) ? 1.0f : 0.0f;
        int bin = (int)ceilf(conf * 15.0f) - 1;
        bin = bin < 0 ? 0 : (bin > 14 ? 14 : bin);

        if (valid && c == bin) {   // lane c owns bin c
            cnt   += 1.0f;
            sconf += conf;
            sacc  += acc;
        }
    }

    __shared__ float sh[48];
    if (tid < 48) sh[tid] = 0.0f;
    __syncthreads();
    if (c < NBINS) {
        atomicAdd(&sh[c],      cnt);
        atomicAdd(&sh[16 + c], sconf);
        atomicAdd(&sh[32 + c], sacc);
    }
    __syncthreads();
    if (tid < 48) {
        atomicAdd(&accum[tid], sh[tid]);
    }
}

__global__ void ece_final(const float* __restrict__ accum, float* __restrict__ out, float nTotal) {
    if (threadIdx.x == 0) {
        float e = 0.0f;
        for (int b = 0; b < NBINS; b++) {
            float cntv = accum[b];
            float sc   = accum[16 + b];
            float sa   = accum[32 + b];
            float safe = fmaxf(cntv, 1.0f);
            float gap  = (cntv > 0.0f) ? fabsf(sc / safe - sa / safe) : 0.0f;
            e += gap * (cntv / nTotal);
        }
        out[0] = e;
    }
}

extern "C" void kernel_launch(void* const* d_in, const int* in_sizes, int n_in,
                              void* d_out, int out_size, void* d_ws, size_t ws_size,
                              hipStream_t stream) {
    const float* logits = (const float*)d_in[0];
    const int*   labels = (const int*)d_in[1];
    const float* temp   = (const float*)d_in[2];
    float* accum = (float*)d_ws;
    const int N = in_sizes[1];   // labels count; logits is N*100

    ece_init<<<1, 64, 0, stream>>>(accum);
    ece_main<<<2048, 256, 0, stream>>>(logits, labels, temp, accum, N);
    ece_final<<<1, 64, 0, stream>>>(accum, (float*)d_out, (float)N);
}

// Round 4
// 174.147 us; speedup vs baseline: 1.0091x; 1.0091x over previous
//
#include <hip/hip_runtime.h>
#include <math.h>

#define NBINS 15

typedef float f32x4 __attribute__((ext_vector_type(4)));

// accum layout in d_ws (48 floats): [0..14] counts, [16..30] sum_conf, [32..46] sum_acc
__global__ void ece_init(float* accum) {
    int t = threadIdx.x;
    if (t < 48) accum[t] = 0.0f;
}

// Process one 4-row group (16 lanes per row). k = invT * log2(e): work in
// exp2 domain (monotone, so argmax/ties unchanged; v_exp_f32 is 2^x).
__device__ __forceinline__ void process4(
    const f32x4* __restrict__ logits4,
    const int* __restrict__ labels,
    long long base, int g, int c, bool has2, float k, int N,
    float& cnt, float& sconf, float& sacc)
{
    long long row = base + g;
    const bool valid = (row < (long long)N);
    const long long r = valid ? row : (long long)(N - 1);
    const f32x4* rowp4 = logits4 + (size_t)r * 25;   // 100 floats = 25 float4

    f32x4 a = __builtin_nontemporal_load(rowp4 + c);
    f32x4 b = (f32x4){-INFINITY, -INFINITY, -INFINITY, -INFINITY};
    if (has2) b = __builtin_nontemporal_load(rowp4 + 16 + c);

    a *= k;
    b *= k;

    // local first-argmax (strict > keeps lowest index on ties)
    float lm = a.x; int lidx = 4 * c;
    if (a.y > lm) { lm = a.y; lidx = 4 * c + 1; }
    if (a.z > lm) { lm = a.z; lidx = 4 * c + 2; }
    if (a.w > lm) { lm = a.w; lidx = 4 * c + 3; }
    if (b.x > lm) { lm = b.x; lidx = 64 + 4 * c; }
    if (b.y > lm) { lm = b.y; lidx = 64 + 4 * c + 1; }
    if (b.z > lm) { lm = b.z; lidx = 64 + 4 * c + 2; }
    if (b.w > lm) { lm = b.w; lidx = 64 + 4 * c + 3; }

    // local exp2-sum vs LOCAL max — off the reduce critical path.
    // exp2(-INF - lm) = 0, so the !has2 lanes contribute 0 from b.
    float s0 = __builtin_amdgcn_exp2f(a.x - lm) + __builtin_amdgcn_exp2f(a.y - lm)
             + __builtin_amdgcn_exp2f(a.z - lm) + __builtin_amdgcn_exp2f(a.w - lm)
             + __builtin_amdgcn_exp2f(b.x - lm) + __builtin_amdgcn_exp2f(b.y - lm)
             + __builtin_amdgcn_exp2f(b.z - lm) + __builtin_amdgcn_exp2f(b.w - lm);

    // 16-lane all-reduce max
    float gm = lm;
    gm = fmaxf(gm, __shfl_xor(gm, 1));
    gm = fmaxf(gm, __shfl_xor(gm, 2));
    gm = fmaxf(gm, __shfl_xor(gm, 4));
    gm = fmaxf(gm, __shfl_xor(gm, 8));

    // first global index achieving gm
    int cand = (lm == gm) ? lidx : 0x7fffffff;
    cand = min(cand, __shfl_xor(cand, 1));
    cand = min(cand, __shfl_xor(cand, 2));
    cand = min(cand, __shfl_xor(cand, 4));
    cand = min(cand, __shfl_xor(cand, 8));

    // rebase local sum to global max, then sum-reduce
    float s = s0 * __builtin_amdgcn_exp2f(lm - gm);
    s += __shfl_xor(s, 1);
    s += __shfl_xor(s, 2);
    s += __shfl_xor(s, 4);
    s += __shfl_xor(s, 8);

    float conf = 1.0f / s;
    int   lbl  = labels[r];
    float acc  = (cand == lbl) ? 1.0f : 0.0f;
    int bin = (int)ceilf(conf * 15.0f) - 1;
    bin = bin < 0 ? 0 : (bin > 14 ? 14 : bin);

    if (valid && c == bin) {   // lane c owns bin c
        cnt   += 1.0f;
        sconf += conf;
        sacc  += acc;
    }
}

__global__ __launch_bounds__(256) void ece_main(
    const float* __restrict__ logits,
    const int* __restrict__ labels,
    const float* __restrict__ temp,
    float* __restrict__ accum,
    int N)
{
    const float k = (1.0f / temp[0]) * 1.44269504088896340736f;  // invT * log2(e)
    const int tid  = threadIdx.x;
    const int lane = tid & 63;
    const int c    = lane & 15;
    const int g    = lane >> 4;
    const int wavesPerBlock = blockDim.x >> 6;
    const long long waveId     = (long long)blockIdx.x * wavesPerBlock + (tid >> 6);
    const long long totalWaves = (long long)gridDim.x * wavesPerBlock;

    const f32x4* logits4 = reinterpret_cast<const f32x4*>(logits);
    float cnt = 0.f, sconf = 0.f, sacc = 0.f;
    const bool has2 = (c < 9);  // 100 floats = 16 float4 + 9 float4

    // 8 rows per wave-iteration: two independent 4-row chains for ILP
    for (long long base = waveId * 8; base < (long long)N; base += totalWaves * 8) {
        process4(logits4, labels, base,     g, c, has2, k, N, cnt, sconf, sacc);
        process4(logits4, labels, base + 4, g, c, has2, k, N, cnt, sconf, sacc);
    }

    __shared__ float sh[48];
    if (tid < 48) sh[tid] = 0.0f;
    __syncthreads();
    if (c < NBINS) {
        atomicAdd(&sh[c],      cnt);
        atomicAdd(&sh[16 + c], sconf);
        atomicAdd(&sh[32 + c], sacc);
    }
    __syncthreads();
    if (tid < 48) {
        atomicAdd(&accum[tid], sh[tid]);
    }
}

__global__ void ece_final(const float* __restrict__ accum, float* __restrict__ out, float nTotal) {
    if (threadIdx.x == 0) {
        float e = 0.0f;
        for (int b = 0; b < NBINS; b++) {
            float cntv = accum[b];
            float sc   = accum[16 + b];
            float sa   = accum[32 + b];
            float safe = fmaxf(cntv, 1.0f);
            float gap  = (cntv > 0.0f) ? fabsf(sc / safe - sa / safe) : 0.0f;
            e += gap * (cntv / nTotal);
        }
        out[0] = e;
    }
}

extern "C" void kernel_launch(void* const* d_in, const int* in_sizes, int n_in,
                              void* d_out, int out_size, void* d_ws, size_t ws_size,
                              hipStream_t stream) {
    const float* logits = (const float*)d_in[0];
    const int*   labels = (const int*)d_in[1];
    const float* temp   = (const float*)d_in[2];
    float* accum = (float*)d_ws;
    const int N = in_sizes[1];   // labels count; logits is N*100

    ece_init<<<1, 64, 0, stream>>>(accum);
    ece_main<<<2048, 256, 0, stream>>>(logits, labels, temp, accum, N);
    ece_final<<<1, 64, 0, stream>>>(accum, (float*)d_out, (float)N);
}